// Round 6
// baseline (81.562 us; speedup 1.0000x reference)
//
#include <hip/hip_runtime.h>

// Reference uses ONLY the last input channel (CIN-1) and matching weight slice:
// out[b,co,h,w] = bias[co] + sum_{kh,kw} x[b,63,h+kh,w+kw] * wt[co,63,kh,kw]
// out (64,64,112,112) f32 = 205.5 MB -> write-BW bound; sustained-fill floor ~30us.
// R2/R4 (NCO=4, plane-split): 39.7us. NCO=8: 42.0us (worse page locality).
// This round: one co per thread, 4 contiguous spatial chunks -> each block
// writes ONE contiguous 16KB region (4x fewer, 4x longer write streams).

#define CB    64
#define CCIN  64
#define CCOUT 64
#define CH    112
#define CW    112
#define CHP   114
#define CWP   114
#define SPT   (CH * (CW/4))   // 3136 float4-groups per (b,co) plane
#define JS    4               // spatial chunks per thread

typedef float v4f __attribute__((ext_vector_type(4)));

__global__ __launch_bounds__(256) void CustomConv2D_12953621365171_kernel(
    const float* __restrict__ x,      // (B, CIN, 114, 114)
    const float* __restrict__ wt,     // (COUT, CIN, 3, 3)
    const float* __restrict__ bias,   // (COUT,)
    float* __restrict__ out)          // (B, COUT, 112, 112)
{
    const int co = blockIdx.y;                    // block-uniform -> SGPR
    const int b  = blockIdx.z;                    // block-uniform -> SGPR
    const int s0 = blockIdx.x * (256 * JS) + threadIdx.x;

    // channel-63 x slice for this batch
    const float* xs = x + ((size_t)b * CCIN + (CCIN - 1)) * (CHP * CWP);
    // channel-63 weights for this co: blockIdx-uniform -> s_load
    const float* wp = wt + ((size_t)co * CCIN + (CCIN - 1)) * 9;
    const float k00 = wp[0], k01 = wp[1], k02 = wp[2];
    const float k10 = wp[3], k11 = wp[4], k12 = wp[5];
    const float k20 = wp[6], k21 = wp[7], k22 = wp[8];
    const float bv  = bias[co];

    float* op = out + ((size_t)b * CCOUT + co) * (CH * CW);

    #pragma unroll
    for (int j = 0; j < JS; ++j) {
        int s = s0 + j * 256;                     // contiguous 1KB burst per wave
        if (s < SPT) {
            int h  = s / 28;                      // magic-mul div
            int wv = s - h * 28;
            int w0 = wv * 4;

            float r[3][6];
            #pragma unroll
            for (int kh = 0; kh < 3; ++kh) {
                const float* row = xs + (h + kh) * CWP + w0;
                __builtin_memcpy(&r[kh][0], row, 6 * sizeof(float));
            }

            float a0 = bv, a1 = bv, a2 = bv, a3 = bv;
            a0 = fmaf(k00, r[0][0], fmaf(k01, r[0][1], fmaf(k02, r[0][2], a0)));
            a1 = fmaf(k00, r[0][1], fmaf(k01, r[0][2], fmaf(k02, r[0][3], a1)));
            a2 = fmaf(k00, r[0][2], fmaf(k01, r[0][3], fmaf(k02, r[0][4], a2)));
            a3 = fmaf(k00, r[0][3], fmaf(k01, r[0][4], fmaf(k02, r[0][5], a3)));
            a0 = fmaf(k10, r[1][0], fmaf(k11, r[1][1], fmaf(k12, r[1][2], a0)));
            a1 = fmaf(k10, r[1][1], fmaf(k11, r[1][2], fmaf(k12, r[1][3], a1)));
            a2 = fmaf(k10, r[1][2], fmaf(k11, r[1][3], fmaf(k12, r[1][4], a2)));
            a3 = fmaf(k10, r[1][3], fmaf(k11, r[1][4], fmaf(k12, r[1][5], a3)));
            a0 = fmaf(k20, r[2][0], fmaf(k21, r[2][1], fmaf(k22, r[2][2], a0)));
            a1 = fmaf(k20, r[2][1], fmaf(k21, r[2][2], fmaf(k22, r[2][3], a1)));
            a2 = fmaf(k20, r[2][2], fmaf(k21, r[2][3], fmaf(k22, r[2][4], a2)));
            a3 = fmaf(k20, r[2][3], fmaf(k21, r[2][4], fmaf(k22, r[2][5], a3)));

            v4f o = { a0, a1, a2, a3 };
            __builtin_nontemporal_store(o, reinterpret_cast<v4f*>(op + (size_t)s * 4));
        }
    }
}

extern "C" void kernel_launch(void* const* d_in, const int* in_sizes, int n_in,
                              void* d_out, int out_size, void* d_ws, size_t ws_size,
                              hipStream_t stream) {
    const float* x    = (const float*)d_in[0];
    const float* wt   = (const float*)d_in[1];
    const float* bias = (const float*)d_in[2];
    float* out = (float*)d_out;

    dim3 grid((SPT + 256 * JS - 1) / (256 * JS),  // 4 (last block 1/16 active)
              CCOUT,                              // 64
              CB);                                // 64  -> 16384 blocks
    dim3 block(256, 1, 1);

    CustomConv2D_12953621365171_kernel<<<grid, block, 0, stream>>>(x, wt, bias, out);
}

// Round 7
// 42.177 us; speedup vs baseline: 1.9338x; 1.9338x over previous
//
#include <hip/hip_runtime.h>

// Reference uses ONLY the last input channel (CIN-1) and matching weight slice:
// out[b,co,h,w] = bias[co] + sum_{kh,kw} x[b,63,h+kh,w+kw] * wt[co,63,kh,kw]
// out (64,64,112,112) f32 = 205.5 MB -> write-BW bound; fill floor ~29.8us.
// History: R2/R4 (NCO=4, direct loads) 39.7us; NCO=8 42us; spatial-JS4 81.6us
// (4x load insts -> 2x time => read path matters). This round: LDS-stage the
// block's x span (aligned dwordx4, each float fetched once), keep R2 stores.

#define CB    64
#define CCIN  64
#define CCOUT 64
#define CH    112
#define CW    112
#define CHP   114
#define CWP   114
#define NCO   4
#define SPT   (CH * (CW/4))      // 3136 float4-groups per (b,co) plane
#define PLANE (CHP * CWP)        // 12996 floats per input plane
#define LDSF  1504               // staged floats (worst case 1484)

typedef float v4f __attribute__((ext_vector_type(4)));
typedef float v2f __attribute__((ext_vector_type(2)));

__global__ __launch_bounds__(256) void CustomConv2D_12953621365171_kernel(
    const float* __restrict__ x,      // (B, CIN, 114, 114)
    const float* __restrict__ wt,     // (COUT, CIN, 3, 3)
    const float* __restrict__ bias,   // (COUT,)
    float* __restrict__ out)          // (B, COUT, 112, 112)
{
    __shared__ float lx[LDSF];

    const int tid = threadIdx.x;
    const int s0b = blockIdx.x * 256;             // first s-group of block
    const int co0 = blockIdx.y * NCO;             // block-uniform -> SGPR
    const int b   = blockIdx.z;                   // block-uniform -> SGPR

    // channel-63 x slice for this batch (16B-aligned: 63*12996*4 % 16 == 0)
    const float* xs = x + ((size_t)b * CCIN + (CCIN - 1)) * PLANE;

    // Rows needed by this block: hlo .. hmax+2 ; stage [off0, end) floats.
    const int hlo  = s0b / 28;
    const int smax = min(SPT - 1, s0b + 255);
    const int hmax = smax / 28;
    const int off0 = (hlo * CWP) & ~3;            // round down -> 16B aligned
    const int end  = (hmax + 3) * CWP;            // exclusive, <= 12996
    const int len  = end - off0;                  // <= 1484

    for (int i = 4 * tid; i < len; i += 1024) {
        if (off0 + i + 4 <= PLANE) {
            *(v4f*)&lx[i] = *(const v4f*)&xs[off0 + i];     // aligned dwordx4
        } else {                                            // tensor-end guard
            for (int k = 0; k < 4 && off0 + i + k < PLANE; ++k)
                lx[i + k] = xs[off0 + i + k];
        }
    }
    __syncthreads();

    const int s = s0b + tid;
    if (s < SPT) {
        int h  = s / 28;                          // magic-mul div
        int wv = s - h * 28;
        int w0 = wv * 4;

        // 18 floats from LDS as 8B-aligned float2 (index always even).
        float r[3][6];
        #pragma unroll
        for (int kh = 0; kh < 3; ++kh) {
            int li = (h + kh) * CWP + w0 - off0;
            v2f p0 = *(const v2f*)&lx[li];
            v2f p1 = *(const v2f*)&lx[li + 2];
            v2f p2 = *(const v2f*)&lx[li + 4];
            r[kh][0] = p0.x; r[kh][1] = p0.y; r[kh][2] = p1.x;
            r[kh][3] = p1.y; r[kh][4] = p2.x; r[kh][5] = p2.y;
        }

        #pragma unroll
        for (int j = 0; j < NCO; ++j) {
            // weights/bias: blockIdx-uniform -> scalar loads
            const float* wp = wt + ((size_t)(co0 + j) * CCIN + (CCIN - 1)) * 9;
            float bv = bias[co0 + j];
            float a0 = bv, a1 = bv, a2 = bv, a3 = bv;
            #pragma unroll
            for (int kh = 0; kh < 3; ++kh) {
                float k0 = wp[kh * 3 + 0];
                float k1 = wp[kh * 3 + 1];
                float k2 = wp[kh * 3 + 2];
                a0 = fmaf(k0, r[kh][0], fmaf(k1, r[kh][1], fmaf(k2, r[kh][2], a0)));
                a1 = fmaf(k0, r[kh][1], fmaf(k1, r[kh][2], fmaf(k2, r[kh][3], a1)));
                a2 = fmaf(k0, r[kh][2], fmaf(k1, r[kh][3], fmaf(k2, r[kh][4], a2)));
                a3 = fmaf(k0, r[kh][3], fmaf(k1, r[kh][4], fmaf(k2, r[kh][5], a3)));
            }
            v4f o = { a0, a1, a2, a3 };
            size_t off = ((size_t)b * CCOUT + (co0 + j)) * (CH * CW) + (size_t)s * 4;
            __builtin_nontemporal_store(o, reinterpret_cast<v4f*>(out + off));
        }
    }
}

extern "C" void kernel_launch(void* const* d_in, const int* in_sizes, int n_in,
                              void* d_out, int out_size, void* d_ws, size_t ws_size,
                              hipStream_t stream) {
    const float* x    = (const float*)d_in[0];
    const float* wt   = (const float*)d_in[1];
    const float* bias = (const float*)d_in[2];
    float* out = (float*)d_out;

    dim3 grid((SPT + 255) / 256,      // 13
              CCOUT / NCO,            // 16
              CB);                    // 64  -> 13312 blocks
    dim3 block(256, 1, 1);

    CustomConv2D_12953621365171_kernel<<<grid, block, 0, stream>>>(x, wt, bias, out);
}